// Round 18
// baseline (630.045 us; speedup 1.0000x reference)
//
#include <hip/hip_runtime.h>
#include <hip/hip_fp16.h>

#define TOKENS 8192
#define INPUT  1024
#define HIDDEN 16384
#define KSEL   32
#define CANDCAP 96
#define TWO_E  0.006f

typedef __attribute__((ext_vector_type(8))) short bf16x8;
typedef __attribute__((ext_vector_type(4))) float f32x4;

#define GLOAD_LDS16(g, l) __builtin_amdgcn_global_load_lds(              \
    (const __attribute__((address_space(1))) void*)(const void*)(g),     \
    (__attribute__((address_space(3))) void*)(void*)(l), 16, 0, 0)

__device__ inline short f2bf(float f) {
    unsigned u = __float_as_uint(f);
    u += 0x7FFFu + ((u >> 16) & 1u);   // RNE
    return (short)(u >> 16);
}

__device__ inline float keyToF(unsigned k) {
    unsigned o = (k & 0x8000u) ? (k ^ 0x8000u) : (~k & 0xFFFFu);
    return __half2float(__ushort_as_half((unsigned short)o));
}

// ---------------- Abf = bf16(x - peb) ----------------
__global__ __launch_bounds__(256) void conv_x(
    const float* __restrict__ x, const float* __restrict__ peb,
    short* __restrict__ Abf)
{
    const int g = (blockIdx.x * 256 + threadIdx.x) * 8;
    const int col = g & (INPUT - 1);
    float4 v0 = *(const float4*)&x[g];
    float4 v1 = *(const float4*)&x[g + 4];
    float4 p0 = *(const float4*)&peb[col];
    float4 p1 = *(const float4*)&peb[col + 4];
    short o[8] = {f2bf(v0.x - p0.x), f2bf(v0.y - p0.y), f2bf(v0.z - p0.z), f2bf(v0.w - p0.w),
                  f2bf(v1.x - p1.x), f2bf(v1.y - p1.y), f2bf(v1.z - p1.z), f2bf(v1.w - p1.w)};
    *(bf16x8*)&Abf[g] = *(bf16x8*)o;
}

// ---------------- Transpose WT -> WTT[HIDDEN][INPUT] fp32 AND Btb bf16 ----------------
__global__ __launch_bounds__(256) void transp2(
    const float* __restrict__ WT, float* __restrict__ WTT, short* __restrict__ Btb)
{
    __shared__ float tl[64][65];
    const int bx = blockIdx.x, by = blockIdx.y;
    const int tid = threadIdx.x;
    const int r0 = tid >> 6, c = tid & 63;
#pragma unroll
    for (int i = 0; i < 16; ++i) {
        int r = i * 4 + r0;
        tl[r][c] = WT[(size_t)(by * 64 + r) * HIDDEN + bx * 64 + c];
    }
    __syncthreads();
#pragma unroll
    for (int i = 0; i < 16; ++i) {
        int a = i * 4 + r0;
        float v = tl[c][a];
        size_t o = (size_t)(bx * 64 + a) * INPUT + by * 64 + c;
        WTT[o] = v;
        Btb[o] = f2bf(v);
    }
}

// ---------------- Whf = fp16(W) ----------------
__global__ __launch_bounds__(256) void conv_whf(
    const float* __restrict__ W, unsigned short* __restrict__ Whf)
{
    const size_t g = ((size_t)blockIdx.x * 256 + threadIdx.x) * 8;
    float4 v0 = *(const float4*)&W[g];
    float4 v1 = *(const float4*)&W[g + 4];
    unsigned short o[8] = {
        __half_as_ushort(__float2half(v0.x)), __half_as_ushort(__float2half(v0.y)),
        __half_as_ushort(__float2half(v0.z)), __half_as_ushort(__float2half(v0.w)),
        __half_as_ushort(__float2half(v1.x)), __half_as_ushort(__float2half(v1.y)),
        __half_as_ushort(__float2half(v1.z)), __half_as_ushort(__float2half(v1.w))};
    *(uint4*)&Whf[g] = *(uint4*)o;
}

// ---------------- 256x256 bf16 MFMA GEMM, 8-phase; R12 bijective XCD swizzle ----------------
__global__ __launch_bounds__(512, 2) void gemm_bf16_256(
    const short* __restrict__ A,   // [TOKENS][INPUT] bf16
    const short* __restrict__ Bt,  // [HIDDEN][INPUT] bf16
    const float* __restrict__ bias1,
    unsigned short* __restrict__ pre16, // [chunkM][HIDDEN] fp16
    int tok0)
{
    __shared__ short lds[65536];
    const char* L = (const char*)lds;
    const int tid = threadIdx.x;
    const int lane = tid & 63;
    const int w = tid >> 6;
    const int wr = w >> 2, wc = w & 3;

    // R12 bijective XCD swizzle: consecutive blocks within an XCD share bm
    // -> A tile L2-resident, B streams once per XCD.
    const int nbx = gridDim.x;            // 64
    const int nwg = nbx * gridDim.y;
    int flat = blockIdx.y * nbx + blockIdx.x;
    flat = (flat & 7) * (nwg >> 3) + (flat >> 3);
    const int bn = flat % nbx, bm = flat / nbx;

    const int row0 = tok0 + bm * 256;
    const int col0 = bn * 256;

    const int xr = (lane & 7) << 4;
    const int koff = (lane >> 4) * 16;
    const int swk0 = koff ^ xr;
    const int swk1 = (64 + koff) ^ xr;
    const int aA0 = (wr * 128 + (lane & 15)) * 128 + swk0;
    const int aA1 = (wr * 128 + (lane & 15)) * 128 + swk1;
    const int aB0 = (wc * 64 + (lane & 15)) * 128 + swk0;
    const int aB1 = (wc * 64 + (lane & 15)) * 128 + swk1;

    const int srd = tid >> 3;
    const int scol = ((tid & 7) * 16) ^ ((srd & 7) << 4);
    const short* Asrc = A  + (size_t)(row0 + srd) * INPUT + (scol >> 1);
    const short* Bsrc = Bt + (size_t)(col0 + srd) * INPUT + (scol >> 1);

    f32x4 acc[8][4];
#pragma unroll
    for (int m = 0; m < 8; ++m)
#pragma unroll
        for (int n = 0; n < 4; ++n) acc[m][n] = (f32x4){0.f, 0.f, 0.f, 0.f};

    auto stageA = [&](int slot, int half, int kt) {
        const size_t so = (size_t)(half * 128) * INPUT + kt * 64;
        short* dst = lds + slot * 32768 + half * 8192 + tid * 8;
        GLOAD_LDS16(Asrc + so, dst);
        GLOAD_LDS16(Asrc + so + (size_t)64 * INPUT, dst + 4096);
    };
    auto stageB = [&](int slot, int half, int kt) {
        const size_t so = (size_t)(half * 128) * INPUT + kt * 64;
        short* dst = lds + slot * 32768 + 16384 + half * 8192 + tid * 8;
        GLOAD_LDS16(Bsrc + so, dst);
        GLOAD_LDS16(Bsrc + so + (size_t)64 * INPUT, dst + 4096);
    };

    bf16x8 AQ[8], BL[4], BH[4];

#define RD_A(SAb, mfbase)                                                       \
    _Pragma("unroll") for (int mf = 0; mf < 4; ++mf) {                          \
        AQ[mf * 2 + 0] = *(const bf16x8*)(L + (SAb) + aA0 + ((mfbase) + mf) * 2048); \
        AQ[mf * 2 + 1] = *(const bf16x8*)(L + (SAb) + aA1 + ((mfbase) + mf) * 2048); \
    }
#define RD_B(SBb, BF, nfbase)                                                   \
    _Pragma("unroll") for (int nf = 0; nf < 2; ++nf) {                          \
        BF[nf * 2 + 0] = *(const bf16x8*)(L + (SBb) + aB0 + ((nfbase) + nf) * 2048); \
        BF[nf * 2 + 1] = *(const bf16x8*)(L + (SBb) + aB1 + ((nfbase) + nf) * 2048); \
    }
#define MFMA_Q(BF, mb, nb)                                                      \
    __builtin_amdgcn_s_setprio(1);                                              \
    _Pragma("unroll") for (int mf = 0; mf < 4; ++mf)                            \
        _Pragma("unroll") for (int nf = 0; nf < 2; ++nf)                        \
            _Pragma("unroll") for (int kk = 0; kk < 2; ++kk)                    \
                acc[(mb) + mf][(nb) + nf] = __builtin_amdgcn_mfma_f32_16x16x32_bf16( \
                    AQ[mf * 2 + kk], BF[nf * 2 + kk], acc[(mb) + mf][(nb) + nf], 0, 0, 0); \
    __builtin_amdgcn_s_setprio(0);
#define BAR()  __builtin_amdgcn_s_barrier()
#define LGKM0() asm volatile("s_waitcnt lgkmcnt(0)" ::: "memory")

    stageA(0, 0, 0); stageA(0, 1, 0);
    stageB(0, 0, 0); stageB(0, 1, 0);
    stageB(1, 0, 1); stageB(1, 1, 1);
    asm volatile("s_waitcnt vmcnt(4)" ::: "memory");
    BAR();

    for (int i = 0; i < 8; ++i) {
        const int kt1 = 2 * i + 1, kt2 = 2 * i + 2, kt3 = 2 * i + 3;
        const bool s2 = kt2 < 16, s3 = kt3 < 16;
        // P1
        RD_A(0, 0); RD_B(32768, BL, 0);
        stageA(1, 0, kt1);
        BAR(); LGKM0();
        MFMA_Q(BL, 0, 0);
        BAR();
        // P2
        RD_B(32768, BH, 2);
        stageA(1, 1, kt1);
        BAR(); LGKM0();
        MFMA_Q(BH, 0, 2);
        BAR();
        // P3
        RD_A(0, 4);
        if (s2) stageB(0, 0, kt2);
        BAR(); LGKM0();
        MFMA_Q(BL, 4, 0);
        BAR();
        // P4
        if (s2) stageB(0, 1, kt2);
        BAR(); LGKM0();
        MFMA_Q(BH, 4, 2);
        if (i < 7) { asm volatile("s_waitcnt vmcnt(4)" ::: "memory"); }
        else       { asm volatile("s_waitcnt vmcnt(0)" ::: "memory"); }
        BAR();
        // P5
        RD_A(65536, 0); RD_B(98304, BL, 0);
        if (s2) stageA(0, 0, kt2);
        BAR(); LGKM0();
        MFMA_Q(BL, 0, 0);
        BAR();
        // P6
        RD_B(98304, BH, 2);
        if (s2) stageA(0, 1, kt2);
        BAR(); LGKM0();
        MFMA_Q(BH, 0, 2);
        BAR();
        // P7
        RD_A(65536, 4);
        if (s3) stageB(1, 0, kt3);
        BAR(); LGKM0();
        MFMA_Q(BL, 4, 0);
        BAR();
        // P8
        if (s3) stageB(1, 1, kt3);
        BAR(); LGKM0();
        MFMA_Q(BH, 4, 2);
        if (i < 7) { asm volatile("s_waitcnt vmcnt(4)" ::: "memory"); }
        BAR();
    }
#undef RD_A
#undef RD_B
#undef MFMA_Q
#undef BAR
#undef LGKM0

    __syncthreads();

    // ---- epilogue: 4-mf batched LDS transpose (4 barriers total) ----
    float bb[4];
#pragma unroll
    for (int nf = 0; nf < 4; ++nf)
        bb[nf] = bias1[col0 + wc * 64 + nf * 16 + (lane & 15)];

    unsigned short* LE = (unsigned short*)lds; // [128][264]
#pragma unroll
    for (int g4 = 0; g4 < 2; ++g4) {
#pragma unroll
        for (int m4 = 0; m4 < 4; ++m4) {
            const int mf = g4 * 4 + m4;
#pragma unroll
            for (int nf = 0; nf < 4; ++nf) {
#pragma unroll
                for (int r = 0; r < 4; ++r) {
                    int er = m4 * 32 + wr * 16 + (lane >> 4) * 4 + r;
                    int ec = wc * 64 + nf * 16 + (lane & 15);
                    LE[er * 264 + ec] = __half_as_ushort(__float2half(acc[mf][nf][r] + bb[nf]));
                }
            }
        }
        __syncthreads();
#pragma unroll
        for (int rd = 0; rd < 8; ++rd) {
            int idx2 = rd * 512 + tid;        // 0..4095
            int el = idx2 >> 5;               // 0..127
            int c8 = (idx2 & 31) * 8;
            int m4 = el >> 5;                 // 0..3
            int er = el & 31;
            int b  = er >> 4;
            int grow = bm * 256 + b * 128 + (g4 * 4 + m4) * 16 + (er & 15);
            uint4 v = *(const uint4*)&LE[el * 264 + c8];
            *(uint4*)&pre16[(size_t)grow * HIDDEN + col0 + c8] = v;
        }
        __syncthreads();
    }
}

// ---------------- Candidate select; parallel prefix compaction ----------------
__global__ __launch_bounds__(256) void topcand3(
    const unsigned short* __restrict__ pre16,
    int* __restrict__ cand, float* __restrict__ scr,
    int* __restrict__ ncand, int tok0)
{
    const int tid = threadIdx.x;
    const int t = blockIdx.x;
    const unsigned short* row = pre16 + (size_t)t * HIDDEN;

    unsigned pk[32];
#pragma unroll
    for (int i = 0; i < 8; ++i) {
        uint4 raw = *(const uint4*)&row[(size_t)tid * 64 + i * 8];
        unsigned rr[4] = {raw.x, raw.y, raw.z, raw.w};
#pragma unroll
        for (int j = 0; j < 4; ++j) {
            unsigned lo16 = rr[j] & 0xFFFFu, hi16 = rr[j] >> 16;
            lo16 ^= (((lo16 >> 15) * 0xFFFFu) | 0x8000u);
            hi16 ^= (((hi16 >> 15) * 0xFFFFu) | 0x8000u);
            pk[i * 4 + j] = lo16 | (hi16 << 16);
        }
    }

    __shared__ unsigned wsum[4];
    const int lane = tid & 63, wid = tid >> 6;

    auto countGE = [&](unsigned tau) -> unsigned {
        unsigned c = 0;
#pragma unroll
        for (int i = 0; i < 32; ++i) {
            c += ((pk[i] & 0xFFFFu) >= tau) ? 1u : 0u;
            c += ((pk[i] >> 16) >= tau) ? 1u : 0u;
        }
#pragma unroll
        for (int s = 32; s > 0; s >>= 1) c += __shfl_xor(c, s, 64);
        if (lane == 0) wsum[wid] = c;
        __syncthreads();
        unsigned tot = wsum[0] + wsum[1] + wsum[2] + wsum[3];
        __syncthreads();
        return tot;
    };

    unsigned lo = 0, hi = 0xFFFFu;
    for (int it = 0; it < 17 && lo < hi; ++it) {
        unsigned mid = (lo + hi + 1) >> 1;
        unsigned c = countGE(mid);
        if (c >= 40u) { lo = mid; if (c <= 48u) break; }
        else hi = mid - 1;
    }
    float v40 = keyToF(lo);
    float vthr = v40 - (TWO_E + 0.002f);
    unsigned kthr = (unsigned)__half_as_ushort(__float2half(vthr));
    kthr ^= (((kthr >> 15) * 0xFFFFu) | 0x8000u);

    unsigned mycnt = 0;
#pragma unroll
    for (int i = 0; i < 32; ++i) {
        mycnt += ((pk[i] & 0xFFFFu) >= kthr) ? 1u : 0u;
        mycnt += ((pk[i] >> 16) >= kthr) ? 1u : 0u;
    }
    unsigned inc = mycnt;
#pragma unroll
    for (int s = 1; s < 64; s <<= 1) {
        unsigned o = __shfl_up(inc, s, 64);
        if (lane >= s) inc += o;
    }
    __shared__ unsigned wtot[4];
    if (lane == 63) wtot[wid] = inc;
    __syncthreads();
    unsigned base = inc - mycnt;
    for (int k = 0; k < wid; ++k) base += wtot[k];
    unsigned tot = wtot[0] + wtot[1] + wtot[2] + wtot[3];

    const int gtok = tok0 + t;
    unsigned pos = base;
#pragma unroll
    for (int i = 0; i < 32; ++i) {
        unsigned l16 = pk[i] & 0xFFFFu, h16 = pk[i] >> 16;
        if (l16 >= kthr) {
            if (pos < CANDCAP) {
                cand[(size_t)gtok * CANDCAP + pos] = tid * 64 + i * 2;
                scr[(size_t)gtok * CANDCAP + pos] = keyToF(l16);
            }
            ++pos;
        }
        if (h16 >= kthr) {
            if (pos < CANDCAP) {
                cand[(size_t)gtok * CANDCAP + pos] = tid * 64 + i * 2 + 1;
                scr[(size_t)gtok * CANDCAP + pos] = keyToF(h16);
            }
            ++pos;
        }
    }
    if (tid == 0) ncand[gtok] = (int)(tot < (unsigned)CANDCAP ? tot : (unsigned)CANDCAP);
}

// ---------------- Wave-per-token f64 rescore -> exact selection ----------------
__global__ __launch_bounds__(256) void rescore_select_wave(
    const float* __restrict__ x, const float* __restrict__ peb,
    const float* __restrict__ WTT, const float* __restrict__ bias1,
    const int* __restrict__ cand, const float* __restrict__ scr,
    const int* __restrict__ ncand,
    float* __restrict__ selv, int* __restrict__ seli)
{
    const int wid = threadIdx.x >> 6, lane = threadIdx.x & 63;
    const int t = blockIdx.x * 4 + wid;

    __shared__ double bexL[4][CANDCAP];
    __shared__ short bandL[4][CANDCAP];

    double xc[16];
#pragma unroll
    for (int st = 0; st < 16; ++st) {
        int j = lane + st * 64;
        xc[st] = (double)x[(size_t)t * INPUT + j] - (double)peb[j];
    }

    const int nc0 = ncand[t];
    const int nc = nc0 < CANDCAP ? nc0 : CANDCAP;

    float sv0 = 0.f, sv1 = 0.f;
    int si0 = 0, si1 = 0;
    const bool a0 = lane < nc, a1 = (64 + lane) < nc;
    if (a0) { sv0 = scr[(size_t)t * CANDCAP + lane]; si0 = cand[(size_t)t * CANDCAP + lane]; }
    if (a1) { sv1 = scr[(size_t)t * CANDCAP + 64 + lane]; si1 = cand[(size_t)t * CANDCAP + 64 + lane]; }

    int r0 = 0, r1 = 0;
    for (int k = 0; k < nc; ++k) {
        float vk; int hk;
        if (k < 64) { vk = __shfl(sv0, k, 64); hk = __shfl(si0, k, 64); }
        else        { vk = __shfl(sv1, k - 64, 64); hk = __shfl(si1, k - 64, 64); }
        if (a0 && (vk > sv0 || (vk == sv0 && hk < si0))) ++r0;
        if (a1 && (vk > sv1 || (vk == sv1 && hk < si1))) ++r1;
    }

    unsigned long long b31_0 = __ballot(a0 && r0 == 31);
    unsigned long long b31_1 = __ballot(a1 && r1 == 31);
    float s32;
    if (b31_0) s32 = __shfl(sv0, (int)__ffsll((long long)b31_0) - 1, 64);
    else       s32 = __shfl(sv1, (int)__ffsll((long long)b31_1) - 1, 64);

    const int f0 = a0 ? ((sv0 > s32 + TWO_E) ? 2 : ((sv0 >= s32 - TWO_E) ? 1 : 0)) : 0;
    const int f1 = a1 ? ((sv1 > s32 + TWO_E) ? 2 : ((sv1 >= s32 - TWO_E) ? 1 : 0)) : 0;

    const unsigned long long mi0 = __ballot(f0 == 2), mi1 = __ballot(f1 == 2);
    const unsigned long long mb0 = __ballot(f0 == 1), mb1 = __ballot(f1 == 1);
    const int nin = __popcll(mi0) + __popcll(mi1);
    const int bn = __popcll(mb0) + __popcll(mb1);
    const int need = KSEL - nin;

    const unsigned long long ltmask = (lane == 63) ? 0x7FFFFFFFFFFFFFFFull
                                                   : ((1ull << lane) - 1ull);
    if (f0 == 1) bandL[wid][__popcll(mb0 & ltmask)] = (short)lane;
    if (f1 == 1) bandL[wid][__popcll(mb0) + __popcll(mb1 & ltmask)] = (short)(64 + lane);

    for (int jb = 0; jb < bn; ++jb) {
        const int c = bandL[wid][jb];
        const int h = (c < 64) ? __shfl(si0, c, 64) : __shfl(si1, c - 64, 64);
        const float* wrow = WTT + (size_t)h * INPUT;
        double s = 0.0;
#pragma unroll
        for (int st = 0; st < 16; ++st)
            s += (double)wrow[lane + st * 64] * xc[st];
#pragma unroll
        for (int off = 32; off > 0; off >>= 1)
            s += __shfl_xor(s, off, 64);
        if (lane == 0) bexL[wid][c] = s + (double)bias1[h];
    }

    int s0 = 0, s1 = 0;
    {
        double v0 = 0.0, v1 = 0.0;
        if (f0 == 1) v0 = bexL[wid][lane];
        if (f1 == 1) v1 = bexL[wid][64 + lane];
        int rb0 = 0, rb1 = 0;
        for (int k = 0; k < bn; ++k) {
            const int ck = bandL[wid][k];
            const int hk = (ck < 64) ? __shfl(si0, ck, 64) : __shfl(si1, ck - 64, 64);
            const double vk = bexL[wid][ck];
            if (f0 == 1 && (vk > v0 || (vk == v0 && hk < si0))) ++rb0;
            if (f1 == 1 && (vk > v1 || (vk == v1 && hk < si1))) ++rb1;
        }
        if (f0 == 2 || (f0 == 1 && rb0 < need)) s0 = 1;
        if (f1 == 2 || (f1 == 1 && rb1 < need)) s1 = 1;

        const unsigned long long ms0 = __ballot(s0), ms1 = __ballot(s1);
        if (s0) {
            int pos = __popcll(ms0 & ltmask);
            if (pos < KSEL) {
                selv[(size_t)t * KSEL + pos] = (f0 == 2) ? sv0 : (float)v0;
                seli[(size_t)t * KSEL + pos] = si0;
            }
        }
        if (s1) {
            int pos = __popcll(ms0) + __popcll(ms1 & ltmask);
            if (pos < KSEL) {
                selv[(size_t)t * KSEL + pos] = (f1 == 2) ? sv1 : (float)v1;
                seli[(size_t)t * KSEL + pos] = si1;
            }
        }
    }
}

// ---------------- Decode: 512 threads, j-range split + LDS combine ----------------
__global__ __launch_bounds__(512) void decode512(
    const float* __restrict__ selv, const int* __restrict__ seli,
    const unsigned short* __restrict__ Whf, const float* __restrict__ b2,
    float* __restrict__ out)
{
    const int t = blockIdx.x;
    const int tid = threadIdx.x;
    const int jh = tid >> 8;          // 0 or 1
    const int cpos = tid & 255;
    const int c = cpos * 4;
    __shared__ float sv[KSEL];
    __shared__ int si[KSEL];
    __shared__ float4 red[256];
    if (tid < KSEL) {
        sv[tid] = selv[(size_t)t * KSEL + tid];
        si[tid] = seli[(size_t)t * KSEL + tid];
    }
    __syncthreads();
    float4 acc = {0.f, 0.f, 0.f, 0.f};
    const int j0 = jh * 16;
#pragma unroll 8
    for (int j = j0; j < j0 + 16; ++j) {
        uint2 raw = *(const uint2*)&Whf[(size_t)si[j] * INPUT + c];
        const float s = sv[j];
        float2 f0 = __half22float2(*(__half2*)&raw.x);
        float2 f1 = __half22float2(*(__half2*)&raw.y);
        acc.x += s * f0.x; acc.y += s * f0.y; acc.z += s * f1.x; acc.w += s * f1.y;
    }
    if (jh == 1) red[cpos] = acc;
    __syncthreads();
    if (jh == 0) {
        float4 o = red[cpos];
        float4 bb = *(const float4*)&b2[c];
        o.x += acc.x + bb.x; o.y += acc.y + bb.y;
        o.z += acc.z + bb.z; o.w += acc.w + bb.w;
        *(float4*)&out[(size_t)t * INPUT + c] = o;
    }
}

extern "C" void kernel_launch(void* const* d_in, const int* in_sizes, int n_in,
                              void* d_out, int out_size, void* d_ws, size_t ws_size,
                              hipStream_t stream) {
    const float* x   = (const float*)d_in[0];
    const float* peb = (const float*)d_in[1];
    const float* W   = (const float*)d_in[2];
    const float* WT  = (const float*)d_in[3];
    const float* b1  = (const float*)d_in[4];
    const float* b2  = (const float*)d_in[5];
    float* out = (float*)d_out;

    char* p = (char*)d_ws;
    int*   candb = (int*)p;            p += (size_t)TOKENS * CANDCAP * 4;
    float* scrb  = (float*)p;          p += (size_t)TOKENS * CANDCAP * 4;
    int*   ncb   = (int*)p;            p += (size_t)TOKENS * 4;
    float* selvb = (float*)p;          p += (size_t)TOKENS * KSEL * 4;
    int*   selib = (int*)p;            p += (size_t)TOKENS * KSEL * 4;
    float* WTT   = (float*)p;          p += (size_t)HIDDEN * INPUT * 4;
    short* Abf   = (short*)p;          p += (size_t)TOKENS * INPUT * 2;
    short* Btb   = (short*)p;          p += (size_t)HIDDEN * INPUT * 2;
    unsigned short* Whf = (unsigned short*)p; p += (size_t)HIDDEN * INPUT * 2;
    unsigned short* pre16 = (unsigned short*)p;

    size_t used = (size_t)(p - (char*)d_ws);
    size_t avail = ws_size > used ? ws_size - used : 0;
    long cap = (long)(avail / ((size_t)HIDDEN * 2));
    cap = (cap / 256) * 256;
    if (cap > 4096) cap = 4096;   // 2 chunks; grid 16x64 = 1024 blocks = 4 exact rounds
    if (cap < 256) cap = 256;

    conv_x<<<dim3(TOKENS * INPUT / (256 * 8)), dim3(256), 0, stream>>>(x, peb, Abf);
    transp2<<<dim3(HIDDEN / 64, INPUT / 64), dim3(256), 0, stream>>>(WT, WTT, Btb);
    conv_whf<<<dim3((unsigned)((size_t)HIDDEN * INPUT / (256 * 8))), dim3(256), 0, stream>>>(W, Whf);

    for (int tok0 = 0; tok0 < TOKENS; tok0 += (int)cap) {
        int M = TOKENS - tok0;
        if (M > cap) M = (int)cap;
        gemm_bf16_256<<<dim3(HIDDEN / 256, M / 256), dim3(512), 0, stream>>>(
            Abf, Btb, b1, pre16, tok0);
        topcand3<<<dim3(M), dim3(256), 0, stream>>>(pre16, candb, scrb, ncb, tok0);
    }

    rescore_select_wave<<<dim3(TOKENS / 4), dim3(256), 0, stream>>>(
        x, peb, WTT, b1, candb, scrb, ncb, selvb, selib);
    decode512<<<dim3(TOKENS), dim3(512), 0, stream>>>(selvb, selib, Whf, b2, out);
}

// Round 19
// 621.355 us; speedup vs baseline: 1.0140x; 1.0140x over previous
//
#include <hip/hip_runtime.h>
#include <hip/hip_fp16.h>

#define TOKENS 8192
#define INPUT  1024
#define HIDDEN 16384
#define KSEL   32
#define CANDCAP 96
#define TWO_E  0.006f

typedef __attribute__((ext_vector_type(8))) short bf16x8;
typedef __attribute__((ext_vector_type(4))) float f32x4;

#define GLOAD_LDS16(g, l) __builtin_amdgcn_global_load_lds(              \
    (const __attribute__((address_space(1))) void*)(const void*)(g),     \
    (__attribute__((address_space(3))) void*)(void*)(l), 16, 0, 0)

__device__ inline short f2bf(float f) {
    unsigned u = __float_as_uint(f);
    u += 0x7FFFu + ((u >> 16) & 1u);   // RNE
    return (short)(u >> 16);
}

__device__ inline float keyToF(unsigned k) {
    unsigned o = (k & 0x8000u) ? (k ^ 0x8000u) : (~k & 0xFFFFu);
    return __half2float(__ushort_as_half((unsigned short)o));
}

// ---------------- Abf = bf16(x - peb) ----------------
__global__ __launch_bounds__(256) void conv_x(
    const float* __restrict__ x, const float* __restrict__ peb,
    short* __restrict__ Abf)
{
    const int g = (blockIdx.x * 256 + threadIdx.x) * 8;
    const int col = g & (INPUT - 1);
    float4 v0 = *(const float4*)&x[g];
    float4 v1 = *(const float4*)&x[g + 4];
    float4 p0 = *(const float4*)&peb[col];
    float4 p1 = *(const float4*)&peb[col + 4];
    short o[8] = {f2bf(v0.x - p0.x), f2bf(v0.y - p0.y), f2bf(v0.z - p0.z), f2bf(v0.w - p0.w),
                  f2bf(v1.x - p1.x), f2bf(v1.y - p1.y), f2bf(v1.z - p1.z), f2bf(v1.w - p1.w)};
    *(bf16x8*)&Abf[g] = *(bf16x8*)o;
}

// ---------------- Transpose WT -> WTT[HIDDEN][INPUT] fp32 AND Btb bf16 ----------------
__global__ __launch_bounds__(256) void transp2(
    const float* __restrict__ WT, float* __restrict__ WTT, short* __restrict__ Btb)
{
    __shared__ float tl[64][65];
    const int bx = blockIdx.x, by = blockIdx.y;
    const int tid = threadIdx.x;
    const int r0 = tid >> 6, c = tid & 63;
#pragma unroll
    for (int i = 0; i < 16; ++i) {
        int r = i * 4 + r0;
        tl[r][c] = WT[(size_t)(by * 64 + r) * HIDDEN + bx * 64 + c];
    }
    __syncthreads();
#pragma unroll
    for (int i = 0; i < 16; ++i) {
        int a = i * 4 + r0;
        float v = tl[c][a];
        size_t o = (size_t)(bx * 64 + a) * INPUT + by * 64 + c;
        WTT[o] = v;
        Btb[o] = f2bf(v);
    }
}

// ---------------- Whf = fp16(W) ----------------
__global__ __launch_bounds__(256) void conv_whf(
    const float* __restrict__ W, unsigned short* __restrict__ Whf)
{
    const size_t g = ((size_t)blockIdx.x * 256 + threadIdx.x) * 8;
    float4 v0 = *(const float4*)&W[g];
    float4 v1 = *(const float4*)&W[g + 4];
    unsigned short o[8] = {
        __half_as_ushort(__float2half(v0.x)), __half_as_ushort(__float2half(v0.y)),
        __half_as_ushort(__float2half(v0.z)), __half_as_ushort(__float2half(v0.w)),
        __half_as_ushort(__float2half(v1.x)), __half_as_ushort(__float2half(v1.y)),
        __half_as_ushort(__float2half(v1.z)), __half_as_ushort(__float2half(v1.w))};
    *(uint4*)&Whf[g] = *(uint4*)o;
}

// ---------------- 256x256 bf16 MFMA GEMM, 8-phase + L2-column XCD map (R17)
//                  + 4-mf batched epilogue (R18) ----------------
__global__ __launch_bounds__(512, 2) void gemm_bf16_256(
    const short* __restrict__ A,   // [TOKENS][INPUT] bf16
    const short* __restrict__ Bt,  // [HIDDEN][INPUT] bf16
    const float* __restrict__ bias1,
    unsigned short* __restrict__ pre16, // [chunkM][HIDDEN] fp16
    int tok0)
{
    __shared__ short lds[65536];
    const char* L = (const char*)lds;
    const int tid = threadIdx.x;
    const int lane = tid & 63;
    const int w = tid >> 6;
    const int wr = w >> 2, wc = w & 3;

    // L2-aware XCD mapping (R17, measured 73.7us/49MB): each XCD owns nbx/8
    // bn-columns across ALL bm; bn varies slowest -> per-XCD B set = 4MB = L2.
    const int nbx = gridDim.x;            // 64
    const int My  = gridDim.y;
    int flat = blockIdx.y * nbx + blockIdx.x;
    const int xcd = flat & 7;
    const int idx = flat >> 3;
    const int colsPerX = nbx >> 3;        // 8
    const int q = idx / My;
    const int bm = idx - q * My;
    const int bn = xcd * colsPerX + q;

    const int row0 = tok0 + bm * 256;
    const int col0 = bn * 256;

    const int xr = (lane & 7) << 4;
    const int koff = (lane >> 4) * 16;
    const int swk0 = koff ^ xr;
    const int swk1 = (64 + koff) ^ xr;
    const int aA0 = (wr * 128 + (lane & 15)) * 128 + swk0;
    const int aA1 = (wr * 128 + (lane & 15)) * 128 + swk1;
    const int aB0 = (wc * 64 + (lane & 15)) * 128 + swk0;
    const int aB1 = (wc * 64 + (lane & 15)) * 128 + swk1;

    const int srd = tid >> 3;
    const int scol = ((tid & 7) * 16) ^ ((srd & 7) << 4);
    const short* Asrc = A  + (size_t)(row0 + srd) * INPUT + (scol >> 1);
    const short* Bsrc = Bt + (size_t)(col0 + srd) * INPUT + (scol >> 1);

    f32x4 acc[8][4];
#pragma unroll
    for (int m = 0; m < 8; ++m)
#pragma unroll
        for (int n = 0; n < 4; ++n) acc[m][n] = (f32x4){0.f, 0.f, 0.f, 0.f};

    auto stageA = [&](int slot, int half, int kt) {
        const size_t so = (size_t)(half * 128) * INPUT + kt * 64;
        short* dst = lds + slot * 32768 + half * 8192 + tid * 8;
        GLOAD_LDS16(Asrc + so, dst);
        GLOAD_LDS16(Asrc + so + (size_t)64 * INPUT, dst + 4096);
    };
    auto stageB = [&](int slot, int half, int kt) {
        const size_t so = (size_t)(half * 128) * INPUT + kt * 64;
        short* dst = lds + slot * 32768 + 16384 + half * 8192 + tid * 8;
        GLOAD_LDS16(Bsrc + so, dst);
        GLOAD_LDS16(Bsrc + so + (size_t)64 * INPUT, dst + 4096);
    };

    bf16x8 AQ[8], BL[4], BH[4];

#define RD_A(SAb, mfbase)                                                       \
    _Pragma("unroll") for (int mf = 0; mf < 4; ++mf) {                          \
        AQ[mf * 2 + 0] = *(const bf16x8*)(L + (SAb) + aA0 + ((mfbase) + mf) * 2048); \
        AQ[mf * 2 + 1] = *(const bf16x8*)(L + (SAb) + aA1 + ((mfbase) + mf) * 2048); \
    }
#define RD_B(SBb, BF, nfbase)                                                   \
    _Pragma("unroll") for (int nf = 0; nf < 2; ++nf) {                          \
        BF[nf * 2 + 0] = *(const bf16x8*)(L + (SBb) + aB0 + ((nfbase) + nf) * 2048); \
        BF[nf * 2 + 1] = *(const bf16x8*)(L + (SBb) + aB1 + ((nfbase) + nf) * 2048); \
    }
#define MFMA_Q(BF, mb, nb)                                                      \
    __builtin_amdgcn_s_setprio(1);                                              \
    _Pragma("unroll") for (int mf = 0; mf < 4; ++mf)                            \
        _Pragma("unroll") for (int nf = 0; nf < 2; ++nf)                        \
            _Pragma("unroll") for (int kk = 0; kk < 2; ++kk)                    \
                acc[(mb) + mf][(nb) + nf] = __builtin_amdgcn_mfma_f32_16x16x32_bf16( \
                    AQ[mf * 2 + kk], BF[nf * 2 + kk], acc[(mb) + mf][(nb) + nf], 0, 0, 0); \
    __builtin_amdgcn_s_setprio(0);
#define BAR()  __builtin_amdgcn_s_barrier()
#define LGKM0() asm volatile("s_waitcnt lgkmcnt(0)" ::: "memory")

    stageA(0, 0, 0); stageA(0, 1, 0);
    stageB(0, 0, 0); stageB(0, 1, 0);
    stageB(1, 0, 1); stageB(1, 1, 1);
    asm volatile("s_waitcnt vmcnt(4)" ::: "memory");
    BAR();

    for (int i = 0; i < 8; ++i) {
        const int kt1 = 2 * i + 1, kt2 = 2 * i + 2, kt3 = 2 * i + 3;
        const bool s2 = kt2 < 16, s3 = kt3 < 16;
        // P1
        RD_A(0, 0); RD_B(32768, BL, 0);
        stageA(1, 0, kt1);
        BAR(); LGKM0();
        MFMA_Q(BL, 0, 0);
        BAR();
        // P2
        RD_B(32768, BH, 2);
        stageA(1, 1, kt1);
        BAR(); LGKM0();
        MFMA_Q(BH, 0, 2);
        BAR();
        // P3
        RD_A(0, 4);
        if (s2) stageB(0, 0, kt2);
        BAR(); LGKM0();
        MFMA_Q(BL, 4, 0);
        BAR();
        // P4
        if (s2) stageB(0, 1, kt2);
        BAR(); LGKM0();
        MFMA_Q(BH, 4, 2);
        if (i < 7) { asm volatile("s_waitcnt vmcnt(4)" ::: "memory"); }
        else       { asm volatile("s_waitcnt vmcnt(0)" ::: "memory"); }
        BAR();
        // P5
        RD_A(65536, 0); RD_B(98304, BL, 0);
        if (s2) stageA(0, 0, kt2);
        BAR(); LGKM0();
        MFMA_Q(BL, 0, 0);
        BAR();
        // P6
        RD_B(98304, BH, 2);
        if (s2) stageA(0, 1, kt2);
        BAR(); LGKM0();
        MFMA_Q(BH, 0, 2);
        BAR();
        // P7
        RD_A(65536, 4);
        if (s3) stageB(1, 0, kt3);
        BAR(); LGKM0();
        MFMA_Q(BL, 4, 0);
        BAR();
        // P8
        if (s3) stageB(1, 1, kt3);
        BAR(); LGKM0();
        MFMA_Q(BH, 4, 2);
        if (i < 7) { asm volatile("s_waitcnt vmcnt(4)" ::: "memory"); }
        BAR();
    }
#undef RD_A
#undef RD_B
#undef MFMA_Q
#undef BAR
#undef LGKM0

    __syncthreads();

    // ---- epilogue: 4-mf batched LDS transpose (4 barriers total, R18) ----
    float bb[4];
#pragma unroll
    for (int nf = 0; nf < 4; ++nf)
        bb[nf] = bias1[col0 + wc * 64 + nf * 16 + (lane & 15)];

    unsigned short* LE = (unsigned short*)lds; // [128][264]
#pragma unroll
    for (int g4 = 0; g4 < 2; ++g4) {
#pragma unroll
        for (int m4 = 0; m4 < 4; ++m4) {
            const int mf = g4 * 4 + m4;
#pragma unroll
            for (int nf = 0; nf < 4; ++nf) {
#pragma unroll
                for (int r = 0; r < 4; ++r) {
                    int er = m4 * 32 + wr * 16 + (lane >> 4) * 4 + r;
                    int ec = wc * 64 + nf * 16 + (lane & 15);
                    LE[er * 264 + ec] = __half_as_ushort(__float2half(acc[mf][nf][r] + bb[nf]));
                }
            }
        }
        __syncthreads();
#pragma unroll
        for (int rd = 0; rd < 8; ++rd) {
            int idx2 = rd * 512 + tid;        // 0..4095
            int el = idx2 >> 5;               // 0..127
            int c8 = (idx2 & 31) * 8;
            int m4 = el >> 5;                 // 0..3
            int er = el & 31;
            int b  = er >> 4;
            int grow = bm * 256 + b * 128 + (g4 * 4 + m4) * 16 + (er & 15);
            uint4 v = *(const uint4*)&LE[el * 264 + c8];
            *(uint4*)&pre16[(size_t)grow * HIDDEN + col0 + c8] = v;
        }
        __syncthreads();
    }
}

// ---------------- Candidate select; parallel prefix compaction ----------------
__global__ __launch_bounds__(256) void topcand3(
    const unsigned short* __restrict__ pre16,
    int* __restrict__ cand, float* __restrict__ scr,
    int* __restrict__ ncand, int tok0)
{
    const int tid = threadIdx.x;
    const int t = blockIdx.x;
    const unsigned short* row = pre16 + (size_t)t * HIDDEN;

    unsigned pk[32];
#pragma unroll
    for (int i = 0; i < 8; ++i) {
        uint4 raw = *(const uint4*)&row[(size_t)tid * 64 + i * 8];
        unsigned rr[4] = {raw.x, raw.y, raw.z, raw.w};
#pragma unroll
        for (int j = 0; j < 4; ++j) {
            unsigned lo16 = rr[j] & 0xFFFFu, hi16 = rr[j] >> 16;
            lo16 ^= (((lo16 >> 15) * 0xFFFFu) | 0x8000u);
            hi16 ^= (((hi16 >> 15) * 0xFFFFu) | 0x8000u);
            pk[i * 4 + j] = lo16 | (hi16 << 16);
        }
    }

    __shared__ unsigned wsum[4];
    const int lane = tid & 63, wid = tid >> 6;

    auto countGE = [&](unsigned tau) -> unsigned {
        unsigned c = 0;
#pragma unroll
        for (int i = 0; i < 32; ++i) {
            c += ((pk[i] & 0xFFFFu) >= tau) ? 1u : 0u;
            c += ((pk[i] >> 16) >= tau) ? 1u : 0u;
        }
#pragma unroll
        for (int s = 32; s > 0; s >>= 1) c += __shfl_xor(c, s, 64);
        if (lane == 0) wsum[wid] = c;
        __syncthreads();
        unsigned tot = wsum[0] + wsum[1] + wsum[2] + wsum[3];
        __syncthreads();
        return tot;
    };

    unsigned lo = 0, hi = 0xFFFFu;
    for (int it = 0; it < 17 && lo < hi; ++it) {
        unsigned mid = (lo + hi + 1) >> 1;
        unsigned c = countGE(mid);
        if (c >= 40u) { lo = mid; if (c <= 48u) break; }
        else hi = mid - 1;
    }
    float v40 = keyToF(lo);
    float vthr = v40 - (TWO_E + 0.002f);
    unsigned kthr = (unsigned)__half_as_ushort(__float2half(vthr));
    kthr ^= (((kthr >> 15) * 0xFFFFu) | 0x8000u);

    unsigned mycnt = 0;
#pragma unroll
    for (int i = 0; i < 32; ++i) {
        mycnt += ((pk[i] & 0xFFFFu) >= kthr) ? 1u : 0u;
        mycnt += ((pk[i] >> 16) >= kthr) ? 1u : 0u;
    }
    unsigned inc = mycnt;
#pragma unroll
    for (int s = 1; s < 64; s <<= 1) {
        unsigned o = __shfl_up(inc, s, 64);
        if (lane >= s) inc += o;
    }
    __shared__ unsigned wtot[4];
    if (lane == 63) wtot[wid] = inc;
    __syncthreads();
    unsigned base = inc - mycnt;
    for (int k = 0; k < wid; ++k) base += wtot[k];
    unsigned tot = wtot[0] + wtot[1] + wtot[2] + wtot[3];

    const int gtok = tok0 + t;
    unsigned pos = base;
#pragma unroll
    for (int i = 0; i < 32; ++i) {
        unsigned l16 = pk[i] & 0xFFFFu, h16 = pk[i] >> 16;
        if (l16 >= kthr) {
            if (pos < CANDCAP) {
                cand[(size_t)gtok * CANDCAP + pos] = tid * 64 + i * 2;
                scr[(size_t)gtok * CANDCAP + pos] = keyToF(l16);
            }
            ++pos;
        }
        if (h16 >= kthr) {
            if (pos < CANDCAP) {
                cand[(size_t)gtok * CANDCAP + pos] = tid * 64 + i * 2 + 1;
                scr[(size_t)gtok * CANDCAP + pos] = keyToF(h16);
            }
            ++pos;
        }
    }
    if (tid == 0) ncand[gtok] = (int)(tot < (unsigned)CANDCAP ? tot : (unsigned)CANDCAP);
}

// ---------------- Wave-per-token f64 rescore -> exact selection ----------------
__global__ __launch_bounds__(256) void rescore_select_wave(
    const float* __restrict__ x, const float* __restrict__ peb,
    const float* __restrict__ WTT, const float* __restrict__ bias1,
    const int* __restrict__ cand, const float* __restrict__ scr,
    const int* __restrict__ ncand,
    float* __restrict__ selv, int* __restrict__ seli)
{
    const int wid = threadIdx.x >> 6, lane = threadIdx.x & 63;
    const int t = blockIdx.x * 4 + wid;

    __shared__ double bexL[4][CANDCAP];
    __shared__ short bandL[4][CANDCAP];

    double xc[16];
#pragma unroll
    for (int st = 0; st < 16; ++st) {
        int j = lane + st * 64;
        xc[st] = (double)x[(size_t)t * INPUT + j] - (double)peb[j];
    }

    const int nc0 = ncand[t];
    const int nc = nc0 < CANDCAP ? nc0 : CANDCAP;

    float sv0 = 0.f, sv1 = 0.f;
    int si0 = 0, si1 = 0;
    const bool a0 = lane < nc, a1 = (64 + lane) < nc;
    if (a0) { sv0 = scr[(size_t)t * CANDCAP + lane]; si0 = cand[(size_t)t * CANDCAP + lane]; }
    if (a1) { sv1 = scr[(size_t)t * CANDCAP + 64 + lane]; si1 = cand[(size_t)t * CANDCAP + 64 + lane]; }

    int r0 = 0, r1 = 0;
    for (int k = 0; k < nc; ++k) {
        float vk; int hk;
        if (k < 64) { vk = __shfl(sv0, k, 64); hk = __shfl(si0, k, 64); }
        else        { vk = __shfl(sv1, k - 64, 64); hk = __shfl(si1, k - 64, 64); }
        if (a0 && (vk > sv0 || (vk == sv0 && hk < si0))) ++r0;
        if (a1 && (vk > sv1 || (vk == sv1 && hk < si1))) ++r1;
    }

    unsigned long long b31_0 = __ballot(a0 && r0 == 31);
    unsigned long long b31_1 = __ballot(a1 && r1 == 31);
    float s32;
    if (b31_0) s32 = __shfl(sv0, (int)__ffsll((long long)b31_0) - 1, 64);
    else       s32 = __shfl(sv1, (int)__ffsll((long long)b31_1) - 1, 64);

    const int f0 = a0 ? ((sv0 > s32 + TWO_E) ? 2 : ((sv0 >= s32 - TWO_E) ? 1 : 0)) : 0;
    const int f1 = a1 ? ((sv1 > s32 + TWO_E) ? 2 : ((sv1 >= s32 - TWO_E) ? 1 : 0)) : 0;

    const unsigned long long mi0 = __ballot(f0 == 2), mi1 = __ballot(f1 == 2);
    const unsigned long long mb0 = __ballot(f0 == 1), mb1 = __ballot(f1 == 1);
    const int nin = __popcll(mi0) + __popcll(mi1);
    const int bn = __popcll(mb0) + __popcll(mb1);
    const int need = KSEL - nin;

    const unsigned long long ltmask = (lane == 63) ? 0x7FFFFFFFFFFFFFFFull
                                                   : ((1ull << lane) - 1ull);
    if (f0 == 1) bandL[wid][__popcll(mb0 & ltmask)] = (short)lane;
    if (f1 == 1) bandL[wid][__popcll(mb0) + __popcll(mb1 & ltmask)] = (short)(64 + lane);

    for (int jb = 0; jb < bn; ++jb) {
        const int c = bandL[wid][jb];
        const int h = (c < 64) ? __shfl(si0, c, 64) : __shfl(si1, c - 64, 64);
        const float* wrow = WTT + (size_t)h * INPUT;
        double s = 0.0;
#pragma unroll
        for (int st = 0; st < 16; ++st)
            s += (double)wrow[lane + st * 64] * xc[st];
#pragma unroll
        for (int off = 32; off > 0; off >>= 1)
            s += __shfl_xor(s, off, 64);
        if (lane == 0) bexL[wid][c] = s + (double)bias1[h];
    }

    int s0 = 0, s1 = 0;
    {
        double v0 = 0.0, v1 = 0.0;
        if (f0 == 1) v0 = bexL[wid][lane];
        if (f1 == 1) v1 = bexL[wid][64 + lane];
        int rb0 = 0, rb1 = 0;
        for (int k = 0; k < bn; ++k) {
            const int ck = bandL[wid][k];
            const int hk = (ck < 64) ? __shfl(si0, ck, 64) : __shfl(si1, ck - 64, 64);
            const double vk = bexL[wid][ck];
            if (f0 == 1 && (vk > v0 || (vk == v0 && hk < si0))) ++rb0;
            if (f1 == 1 && (vk > v1 || (vk == v1 && hk < si1))) ++rb1;
        }
        if (f0 == 2 || (f0 == 1 && rb0 < need)) s0 = 1;
        if (f1 == 2 || (f1 == 1 && rb1 < need)) s1 = 1;

        const unsigned long long ms0 = __ballot(s0), ms1 = __ballot(s1);
        if (s0) {
            int pos = __popcll(ms0 & ltmask);
            if (pos < KSEL) {
                selv[(size_t)t * KSEL + pos] = (f0 == 2) ? sv0 : (float)v0;
                seli[(size_t)t * KSEL + pos] = si0;
            }
        }
        if (s1) {
            int pos = __popcll(ms0) + __popcll(ms1 & ltmask);
            if (pos < KSEL) {
                selv[(size_t)t * KSEL + pos] = (f1 == 2) ? sv1 : (float)v1;
                seli[(size_t)t * KSEL + pos] = si1;
            }
        }
    }
}

// ---------------- Decode: 512 threads, j-range split + LDS combine ----------------
__global__ __launch_bounds__(512) void decode512(
    const float* __restrict__ selv, const int* __restrict__ seli,
    const unsigned short* __restrict__ Whf, const float* __restrict__ b2,
    float* __restrict__ out)
{
    const int t = blockIdx.x;
    const int tid = threadIdx.x;
    const int jh = tid >> 8;          // 0 or 1
    const int cpos = tid & 255;
    const int c = cpos * 4;
    __shared__ float sv[KSEL];
    __shared__ int si[KSEL];
    __shared__ float4 red[256];
    if (tid < KSEL) {
        sv[tid] = selv[(size_t)t * KSEL + tid];
        si[tid] = seli[(size_t)t * KSEL + tid];
    }
    __syncthreads();
    float4 acc = {0.f, 0.f, 0.f, 0.f};
    const int j0 = jh * 16;
#pragma unroll 8
    for (int j = j0; j < j0 + 16; ++j) {
        uint2 raw = *(const uint2*)&Whf[(size_t)si[j] * INPUT + c];
        const float s = sv[j];
        float2 f0 = __half22float2(*(__half2*)&raw.x);
        float2 f1 = __half22float2(*(__half2*)&raw.y);
        acc.x += s * f0.x; acc.y += s * f0.y; acc.z += s * f1.x; acc.w += s * f1.y;
    }
    if (jh == 1) red[cpos] = acc;
    __syncthreads();
    if (jh == 0) {
        float4 o = red[cpos];
        float4 bb = *(const float4*)&b2[c];
        o.x += acc.x + bb.x; o.y += acc.y + bb.y;
        o.z += acc.z + bb.z; o.w += acc.w + bb.w;
        *(float4*)&out[(size_t)t * INPUT + c] = o;
    }
}

extern "C" void kernel_launch(void* const* d_in, const int* in_sizes, int n_in,
                              void* d_out, int out_size, void* d_ws, size_t ws_size,
                              hipStream_t stream) {
    const float* x   = (const float*)d_in[0];
    const float* peb = (const float*)d_in[1];
    const float* W   = (const float*)d_in[2];
    const float* WT  = (const float*)d_in[3];
    const float* b1  = (const float*)d_in[4];
    const float* b2  = (const float*)d_in[5];
    float* out = (float*)d_out;

    char* p = (char*)d_ws;
    int*   candb = (int*)p;            p += (size_t)TOKENS * CANDCAP * 4;
    float* scrb  = (float*)p;          p += (size_t)TOKENS * CANDCAP * 4;
    int*   ncb   = (int*)p;            p += (size_t)TOKENS * 4;
    float* selvb = (float*)p;          p += (size_t)TOKENS * KSEL * 4;
    int*   selib = (int*)p;            p += (size_t)TOKENS * KSEL * 4;
    float* WTT   = (float*)p;          p += (size_t)HIDDEN * INPUT * 4;
    short* Abf   = (short*)p;          p += (size_t)TOKENS * INPUT * 2;
    short* Btb   = (short*)p;          p += (size_t)HIDDEN * INPUT * 2;
    unsigned short* Whf = (unsigned short*)p; p += (size_t)HIDDEN * INPUT * 2;
    unsigned short* pre16 = (unsigned short*)p;

    size_t used = (size_t)(p - (char*)d_ws);
    size_t avail = ws_size > used ? ws_size - used : 0;
    long cap = (long)(avail / ((size_t)HIDDEN * 2));
    cap = (cap / 256) * 256;
    if (cap > 2048) cap = 2048;   // grid 8x64 = 512 blocks = exactly 2 rounds/CU
    if (cap < 256) cap = 256;

    conv_x<<<dim3(TOKENS * INPUT / (256 * 8)), dim3(256), 0, stream>>>(x, peb, Abf);
    transp2<<<dim3(HIDDEN / 64, INPUT / 64), dim3(256), 0, stream>>>(WT, WTT, Btb);
    conv_whf<<<dim3((unsigned)((size_t)HIDDEN * INPUT / (256 * 8))), dim3(256), 0, stream>>>(W, Whf);

    for (int tok0 = 0; tok0 < TOKENS; tok0 += (int)cap) {
        int M = TOKENS - tok0;
        if (M > cap) M = (int)cap;
        gemm_bf16_256<<<dim3(HIDDEN / 256, M / 256), dim3(512), 0, stream>>>(
            Abf, Btb, b1, pre16, tok0);
        topcand3<<<dim3(M), dim3(256), 0, stream>>>(pre16, candb, scrb, ncb, tok0);
    }

    rescore_select_wave<<<dim3(TOKENS / 4), dim3(256), 0, stream>>>(
        x, peb, WTT, b1, candb, scrb, ncb, selvb, selib);
    decode512<<<dim3(TOKENS), dim3(512), 0, stream>>>(selvb, selib, Whf, b2, out);
}

// Round 20
// 608.723 us; speedup vs baseline: 1.0350x; 1.0208x over previous
//
#include <hip/hip_runtime.h>
#include <hip/hip_fp16.h>

#define TOKENS 8192
#define INPUT  1024
#define HIDDEN 16384
#define KSEL   32
#define CANDCAP 96
#define TWO_E  0.006f

typedef __attribute__((ext_vector_type(8))) short bf16x8;
typedef __attribute__((ext_vector_type(4))) float f32x4;

#define GLOAD_LDS16(g, l) __builtin_amdgcn_global_load_lds(              \
    (const __attribute__((address_space(1))) void*)(const void*)(g),     \
    (__attribute__((address_space(3))) void*)(void*)(l), 16, 0, 0)

__device__ inline short f2bf(float f) {
    unsigned u = __float_as_uint(f);
    u += 0x7FFFu + ((u >> 16) & 1u);   // RNE
    return (short)(u >> 16);
}

__device__ inline float keyToF(unsigned k) {
    unsigned o = (k & 0x8000u) ? (k ^ 0x8000u) : (~k & 0xFFFFu);
    return __half2float(__ushort_as_half((unsigned short)o));
}

// ---------------- Abf = bf16(x - peb) ----------------
__global__ __launch_bounds__(256) void conv_x(
    const float* __restrict__ x, const float* __restrict__ peb,
    short* __restrict__ Abf)
{
    const int g = (blockIdx.x * 256 + threadIdx.x) * 8;
    const int col = g & (INPUT - 1);
    float4 v0 = *(const float4*)&x[g];
    float4 v1 = *(const float4*)&x[g + 4];
    float4 p0 = *(const float4*)&peb[col];
    float4 p1 = *(const float4*)&peb[col + 4];
    short o[8] = {f2bf(v0.x - p0.x), f2bf(v0.y - p0.y), f2bf(v0.z - p0.z), f2bf(v0.w - p0.w),
                  f2bf(v1.x - p1.x), f2bf(v1.y - p1.y), f2bf(v1.z - p1.z), f2bf(v1.w - p1.w)};
    *(bf16x8*)&Abf[g] = *(bf16x8*)o;
}

// ---------------- Transpose WT -> WTT[HIDDEN][INPUT] fp32 AND Btb bf16 ----------------
__global__ __launch_bounds__(256) void transp2(
    const float* __restrict__ WT, float* __restrict__ WTT, short* __restrict__ Btb)
{
    __shared__ float tl[64][65];
    const int bx = blockIdx.x, by = blockIdx.y;
    const int tid = threadIdx.x;
    const int r0 = tid >> 6, c = tid & 63;
#pragma unroll
    for (int i = 0; i < 16; ++i) {
        int r = i * 4 + r0;
        tl[r][c] = WT[(size_t)(by * 64 + r) * HIDDEN + bx * 64 + c];
    }
    __syncthreads();
#pragma unroll
    for (int i = 0; i < 16; ++i) {
        int a = i * 4 + r0;
        float v = tl[c][a];
        size_t o = (size_t)(bx * 64 + a) * INPUT + by * 64 + c;
        WTT[o] = v;
        Btb[o] = f2bf(v);
    }
}

// ---------------- Whf = fp16(W) ----------------
__global__ __launch_bounds__(256) void conv_whf(
    const float* __restrict__ W, unsigned short* __restrict__ Whf)
{
    const size_t g = ((size_t)blockIdx.x * 256 + threadIdx.x) * 8;
    float4 v0 = *(const float4*)&W[g];
    float4 v1 = *(const float4*)&W[g + 4];
    unsigned short o[8] = {
        __half_as_ushort(__float2half(v0.x)), __half_as_ushort(__float2half(v0.y)),
        __half_as_ushort(__float2half(v0.z)), __half_as_ushort(__float2half(v0.w)),
        __half_as_ushort(__float2half(v1.x)), __half_as_ushort(__float2half(v1.y)),
        __half_as_ushort(__float2half(v1.z)), __half_as_ushort(__float2half(v1.w))};
    *(uint4*)&Whf[g] = *(uint4*)o;
}

// ---------------- 256x256 bf16 MFMA GEMM, 8-phase + L2-column XCD map
//                  + 4-mf batched epilogue ----------------
__global__ __launch_bounds__(512, 2) void gemm_bf16_256(
    const short* __restrict__ A,   // [TOKENS][INPUT] bf16
    const short* __restrict__ Bt,  // [HIDDEN][INPUT] bf16
    const float* __restrict__ bias1,
    unsigned short* __restrict__ pre16, // [chunkM][HIDDEN] fp16
    int tok0)
{
    __shared__ short lds[65536];
    const char* L = (const char*)lds;
    const int tid = threadIdx.x;
    const int lane = tid & 63;
    const int w = tid >> 6;
    const int wr = w >> 2, wc = w & 3;

    // L2-aware XCD mapping (measured 73.7us/49MB @2 rounds): each XCD owns
    // nbx/8 bn-columns across ALL bm; bn varies slowest -> per-XCD B set = 4MB.
    const int nbx = gridDim.x;            // 64
    const int My  = gridDim.y;
    int flat = blockIdx.y * nbx + blockIdx.x;
    const int xcd = flat & 7;
    const int idx = flat >> 3;
    const int colsPerX = nbx >> 3;        // 8
    const int q = idx / My;
    const int bm = idx - q * My;
    const int bn = xcd * colsPerX + q;

    const int row0 = tok0 + bm * 256;
    const int col0 = bn * 256;

    const int xr = (lane & 7) << 4;
    const int koff = (lane >> 4) * 16;
    const int swk0 = koff ^ xr;
    const int swk1 = (64 + koff) ^ xr;
    const int aA0 = (wr * 128 + (lane & 15)) * 128 + swk0;
    const int aA1 = (wr * 128 + (lane & 15)) * 128 + swk1;
    const int aB0 = (wc * 64 + (lane & 15)) * 128 + swk0;
    const int aB1 = (wc * 64 + (lane & 15)) * 128 + swk1;

    const int srd = tid >> 3;
    const int scol = ((tid & 7) * 16) ^ ((srd & 7) << 4);
    const short* Asrc = A  + (size_t)(row0 + srd) * INPUT + (scol >> 1);
    const short* Bsrc = Bt + (size_t)(col0 + srd) * INPUT + (scol >> 1);

    f32x4 acc[8][4];
#pragma unroll
    for (int m = 0; m < 8; ++m)
#pragma unroll
        for (int n = 0; n < 4; ++n) acc[m][n] = (f32x4){0.f, 0.f, 0.f, 0.f};

    auto stageA = [&](int slot, int half, int kt) {
        const size_t so = (size_t)(half * 128) * INPUT + kt * 64;
        short* dst = lds + slot * 32768 + half * 8192 + tid * 8;
        GLOAD_LDS16(Asrc + so, dst);
        GLOAD_LDS16(Asrc + so + (size_t)64 * INPUT, dst + 4096);
    };
    auto stageB = [&](int slot, int half, int kt) {
        const size_t so = (size_t)(half * 128) * INPUT + kt * 64;
        short* dst = lds + slot * 32768 + 16384 + half * 8192 + tid * 8;
        GLOAD_LDS16(Bsrc + so, dst);
        GLOAD_LDS16(Bsrc + so + (size_t)64 * INPUT, dst + 4096);
    };

    bf16x8 AQ[8], BL[4], BH[4];

#define RD_A(SAb, mfbase)                                                       \
    _Pragma("unroll") for (int mf = 0; mf < 4; ++mf) {                          \
        AQ[mf * 2 + 0] = *(const bf16x8*)(L + (SAb) + aA0 + ((mfbase) + mf) * 2048); \
        AQ[mf * 2 + 1] = *(const bf16x8*)(L + (SAb) + aA1 + ((mfbase) + mf) * 2048); \
    }
#define RD_B(SBb, BF, nfbase)                                                   \
    _Pragma("unroll") for (int nf = 0; nf < 2; ++nf) {                          \
        BF[nf * 2 + 0] = *(const bf16x8*)(L + (SBb) + aB0 + ((nfbase) + nf) * 2048); \
        BF[nf * 2 + 1] = *(const bf16x8*)(L + (SBb) + aB1 + ((nfbase) + nf) * 2048); \
    }
#define MFMA_Q(BF, mb, nb)                                                      \
    __builtin_amdgcn_s_setprio(1);                                              \
    _Pragma("unroll") for (int mf = 0; mf < 4; ++mf)                            \
        _Pragma("unroll") for (int nf = 0; nf < 2; ++nf)                        \
            _Pragma("unroll") for (int kk = 0; kk < 2; ++kk)                    \
                acc[(mb) + mf][(nb) + nf] = __builtin_amdgcn_mfma_f32_16x16x32_bf16( \
                    AQ[mf * 2 + kk], BF[nf * 2 + kk], acc[(mb) + mf][(nb) + nf], 0, 0, 0); \
    __builtin_amdgcn_s_setprio(0);
#define BAR()  __builtin_amdgcn_s_barrier()
#define LGKM0() asm volatile("s_waitcnt lgkmcnt(0)" ::: "memory")

    stageA(0, 0, 0); stageA(0, 1, 0);
    stageB(0, 0, 0); stageB(0, 1, 0);
    stageB(1, 0, 1); stageB(1, 1, 1);
    asm volatile("s_waitcnt vmcnt(4)" ::: "memory");
    BAR();

    for (int i = 0; i < 8; ++i) {
        const int kt1 = 2 * i + 1, kt2 = 2 * i + 2, kt3 = 2 * i + 3;
        const bool s2 = kt2 < 16, s3 = kt3 < 16;
        // P1
        RD_A(0, 0); RD_B(32768, BL, 0);
        stageA(1, 0, kt1);
        BAR(); LGKM0();
        MFMA_Q(BL, 0, 0);
        BAR();
        // P2
        RD_B(32768, BH, 2);
        stageA(1, 1, kt1);
        BAR(); LGKM0();
        MFMA_Q(BH, 0, 2);
        BAR();
        // P3
        RD_A(0, 4);
        if (s2) stageB(0, 0, kt2);
        BAR(); LGKM0();
        MFMA_Q(BL, 4, 0);
        BAR();
        // P4
        if (s2) stageB(0, 1, kt2);
        BAR(); LGKM0();
        MFMA_Q(BH, 4, 2);
        if (i < 7) { asm volatile("s_waitcnt vmcnt(4)" ::: "memory"); }
        else       { asm volatile("s_waitcnt vmcnt(0)" ::: "memory"); }
        BAR();
        // P5
        RD_A(65536, 0); RD_B(98304, BL, 0);
        if (s2) stageA(0, 0, kt2);
        BAR(); LGKM0();
        MFMA_Q(BL, 0, 0);
        BAR();
        // P6
        RD_B(98304, BH, 2);
        if (s2) stageA(0, 1, kt2);
        BAR(); LGKM0();
        MFMA_Q(BH, 0, 2);
        BAR();
        // P7
        RD_A(65536, 4);
        if (s3) stageB(1, 0, kt3);
        BAR(); LGKM0();
        MFMA_Q(BL, 4, 0);
        BAR();
        // P8
        if (s3) stageB(1, 1, kt3);
        BAR(); LGKM0();
        MFMA_Q(BH, 4, 2);
        if (i < 7) { asm volatile("s_waitcnt vmcnt(4)" ::: "memory"); }
        BAR();
    }
#undef RD_A
#undef RD_B
#undef MFMA_Q
#undef BAR
#undef LGKM0

    __syncthreads();

    // ---- epilogue: 4-mf batched LDS transpose (4 barriers total) ----
    float bb[4];
#pragma unroll
    for (int nf = 0; nf < 4; ++nf)
        bb[nf] = bias1[col0 + wc * 64 + nf * 16 + (lane & 15)];

    unsigned short* LE = (unsigned short*)lds; // [128][264]
#pragma unroll
    for (int g4 = 0; g4 < 2; ++g4) {
#pragma unroll
        for (int m4 = 0; m4 < 4; ++m4) {
            const int mf = g4 * 4 + m4;
#pragma unroll
            for (int nf = 0; nf < 4; ++nf) {
#pragma unroll
                for (int r = 0; r < 4; ++r) {
                    int er = m4 * 32 + wr * 16 + (lane >> 4) * 4 + r;
                    int ec = wc * 64 + nf * 16 + (lane & 15);
                    LE[er * 264 + ec] = __half_as_ushort(__float2half(acc[mf][nf][r] + bb[nf]));
                }
            }
        }
        __syncthreads();
#pragma unroll
        for (int rd = 0; rd < 8; ++rd) {
            int idx2 = rd * 512 + tid;        // 0..4095
            int el = idx2 >> 5;               // 0..127
            int c8 = (idx2 & 31) * 8;
            int m4 = el >> 5;                 // 0..3
            int er = el & 31;
            int b  = er >> 4;
            int grow = bm * 256 + b * 128 + (g4 * 4 + m4) * 16 + (er & 15);
            uint4 v = *(const uint4*)&LE[el * 264 + c8];
            *(uint4*)&pre16[(size_t)grow * HIDDEN + col0 + c8] = v;
        }
        __syncthreads();
    }
}

// ---------------- Candidate select; parallel prefix compaction ----------------
__global__ __launch_bounds__(256) void topcand3(
    const unsigned short* __restrict__ pre16,
    int* __restrict__ cand, float* __restrict__ scr,
    int* __restrict__ ncand, int tok0)
{
    const int tid = threadIdx.x;
    const int t = blockIdx.x;
    const unsigned short* row = pre16 + (size_t)t * HIDDEN;

    unsigned pk[32];
#pragma unroll
    for (int i = 0; i < 8; ++i) {
        uint4 raw = *(const uint4*)&row[(size_t)tid * 64 + i * 8];
        unsigned rr[4] = {raw.x, raw.y, raw.z, raw.w};
#pragma unroll
        for (int j = 0; j < 4; ++j) {
            unsigned lo16 = rr[j] & 0xFFFFu, hi16 = rr[j] >> 16;
            lo16 ^= (((lo16 >> 15) * 0xFFFFu) | 0x8000u);
            hi16 ^= (((hi16 >> 15) * 0xFFFFu) | 0x8000u);
            pk[i * 4 + j] = lo16 | (hi16 << 16);
        }
    }

    __shared__ unsigned wsum[4];
    const int lane = tid & 63, wid = tid >> 6;

    auto countGE = [&](unsigned tau) -> unsigned {
        unsigned c = 0;
#pragma unroll
        for (int i = 0; i < 32; ++i) {
            c += ((pk[i] & 0xFFFFu) >= tau) ? 1u : 0u;
            c += ((pk[i] >> 16) >= tau) ? 1u : 0u;
        }
#pragma unroll
        for (int s = 32; s > 0; s >>= 1) c += __shfl_xor(c, s, 64);
        if (lane == 0) wsum[wid] = c;
        __syncthreads();
        unsigned tot = wsum[0] + wsum[1] + wsum[2] + wsum[3];
        __syncthreads();
        return tot;
    };

    unsigned lo = 0, hi = 0xFFFFu;
    for (int it = 0; it < 17 && lo < hi; ++it) {
        unsigned mid = (lo + hi + 1) >> 1;
        unsigned c = countGE(mid);
        if (c >= 40u) { lo = mid; if (c <= 48u) break; }
        else hi = mid - 1;
    }
    float v40 = keyToF(lo);
    float vthr = v40 - (TWO_E + 0.002f);
    unsigned kthr = (unsigned)__half_as_ushort(__float2half(vthr));
    kthr ^= (((kthr >> 15) * 0xFFFFu) | 0x8000u);

    unsigned mycnt = 0;
#pragma unroll
    for (int i = 0; i < 32; ++i) {
        mycnt += ((pk[i] & 0xFFFFu) >= kthr) ? 1u : 0u;
        mycnt += ((pk[i] >> 16) >= kthr) ? 1u : 0u;
    }
    unsigned inc = mycnt;
#pragma unroll
    for (int s = 1; s < 64; s <<= 1) {
        unsigned o = __shfl_up(inc, s, 64);
        if (lane >= s) inc += o;
    }
    __shared__ unsigned wtot[4];
    if (lane == 63) wtot[wid] = inc;
    __syncthreads();
    unsigned base = inc - mycnt;
    for (int k = 0; k < wid; ++k) base += wtot[k];
    unsigned tot = wtot[0] + wtot[1] + wtot[2] + wtot[3];

    const int gtok = tok0 + t;
    unsigned pos = base;
#pragma unroll
    for (int i = 0; i < 32; ++i) {
        unsigned l16 = pk[i] & 0xFFFFu, h16 = pk[i] >> 16;
        if (l16 >= kthr) {
            if (pos < CANDCAP) {
                cand[(size_t)gtok * CANDCAP + pos] = tid * 64 + i * 2;
                scr[(size_t)gtok * CANDCAP + pos] = keyToF(l16);
            }
            ++pos;
        }
        if (h16 >= kthr) {
            if (pos < CANDCAP) {
                cand[(size_t)gtok * CANDCAP + pos] = tid * 64 + i * 2 + 1;
                scr[(size_t)gtok * CANDCAP + pos] = keyToF(h16);
            }
            ++pos;
        }
    }
    if (tid == 0) ncand[gtok] = (int)(tot < (unsigned)CANDCAP ? tot : (unsigned)CANDCAP);
}

// ---------------- Wave-per-token f64 rescore -> exact selection ----------------
__global__ __launch_bounds__(256) void rescore_select_wave(
    const float* __restrict__ x, const float* __restrict__ peb,
    const float* __restrict__ WTT, const float* __restrict__ bias1,
    const int* __restrict__ cand, const float* __restrict__ scr,
    const int* __restrict__ ncand,
    float* __restrict__ selv, int* __restrict__ seli)
{
    const int wid = threadIdx.x >> 6, lane = threadIdx.x & 63;
    const int t = blockIdx.x * 4 + wid;

    __shared__ double bexL[4][CANDCAP];
    __shared__ short bandL[4][CANDCAP];

    double xc[16];
#pragma unroll
    for (int st = 0; st < 16; ++st) {
        int j = lane + st * 64;
        xc[st] = (double)x[(size_t)t * INPUT + j] - (double)peb[j];
    }

    const int nc0 = ncand[t];
    const int nc = nc0 < CANDCAP ? nc0 : CANDCAP;

    float sv0 = 0.f, sv1 = 0.f;
    int si0 = 0, si1 = 0;
    const bool a0 = lane < nc, a1 = (64 + lane) < nc;
    if (a0) { sv0 = scr[(size_t)t * CANDCAP + lane]; si0 = cand[(size_t)t * CANDCAP + lane]; }
    if (a1) { sv1 = scr[(size_t)t * CANDCAP + 64 + lane]; si1 = cand[(size_t)t * CANDCAP + 64 + lane]; }

    int r0 = 0, r1 = 0;
    for (int k = 0; k < nc; ++k) {
        float vk; int hk;
        if (k < 64) { vk = __shfl(sv0, k, 64); hk = __shfl(si0, k, 64); }
        else        { vk = __shfl(sv1, k - 64, 64); hk = __shfl(si1, k - 64, 64); }
        if (a0 && (vk > sv0 || (vk == sv0 && hk < si0))) ++r0;
        if (a1 && (vk > sv1 || (vk == sv1 && hk < si1))) ++r1;
    }

    unsigned long long b31_0 = __ballot(a0 && r0 == 31);
    unsigned long long b31_1 = __ballot(a1 && r1 == 31);
    float s32;
    if (b31_0) s32 = __shfl(sv0, (int)__ffsll((long long)b31_0) - 1, 64);
    else       s32 = __shfl(sv1, (int)__ffsll((long long)b31_1) - 1, 64);

    const int f0 = a0 ? ((sv0 > s32 + TWO_E) ? 2 : ((sv0 >= s32 - TWO_E) ? 1 : 0)) : 0;
    const int f1 = a1 ? ((sv1 > s32 + TWO_E) ? 2 : ((sv1 >= s32 - TWO_E) ? 1 : 0)) : 0;

    const unsigned long long mi0 = __ballot(f0 == 2), mi1 = __ballot(f1 == 2);
    const unsigned long long mb0 = __ballot(f0 == 1), mb1 = __ballot(f1 == 1);
    const int nin = __popcll(mi0) + __popcll(mi1);
    const int bn = __popcll(mb0) + __popcll(mb1);
    const int need = KSEL - nin;

    const unsigned long long ltmask = (lane == 63) ? 0x7FFFFFFFFFFFFFFFull
                                                   : ((1ull << lane) - 1ull);
    if (f0 == 1) bandL[wid][__popcll(mb0 & ltmask)] = (short)lane;
    if (f1 == 1) bandL[wid][__popcll(mb0) + __popcll(mb1 & ltmask)] = (short)(64 + lane);

    for (int jb = 0; jb < bn; ++jb) {
        const int c = bandL[wid][jb];
        const int h = (c < 64) ? __shfl(si0, c, 64) : __shfl(si1, c - 64, 64);
        const float* wrow = WTT + (size_t)h * INPUT;
        double s = 0.0;
#pragma unroll
        for (int st = 0; st < 16; ++st)
            s += (double)wrow[lane + st * 64] * xc[st];
#pragma unroll
        for (int off = 32; off > 0; off >>= 1)
            s += __shfl_xor(s, off, 64);
        if (lane == 0) bexL[wid][c] = s + (double)bias1[h];
    }

    int s0 = 0, s1 = 0;
    {
        double v0 = 0.0, v1 = 0.0;
        if (f0 == 1) v0 = bexL[wid][lane];
        if (f1 == 1) v1 = bexL[wid][64 + lane];
        int rb0 = 0, rb1 = 0;
        for (int k = 0; k < bn; ++k) {
            const int ck = bandL[wid][k];
            const int hk = (ck < 64) ? __shfl(si0, ck, 64) : __shfl(si1, ck - 64, 64);
            const double vk = bexL[wid][ck];
            if (f0 == 1 && (vk > v0 || (vk == v0 && hk < si0))) ++rb0;
            if (f1 == 1 && (vk > v1 || (vk == v1 && hk < si1))) ++rb1;
        }
        if (f0 == 2 || (f0 == 1 && rb0 < need)) s0 = 1;
        if (f1 == 2 || (f1 == 1 && rb1 < need)) s1 = 1;

        const unsigned long long ms0 = __ballot(s0), ms1 = __ballot(s1);
        if (s0) {
            int pos = __popcll(ms0 & ltmask);
            if (pos < KSEL) {
                selv[(size_t)t * KSEL + pos] = (f0 == 2) ? sv0 : (float)v0;
                seli[(size_t)t * KSEL + pos] = si0;
            }
        }
        if (s1) {
            int pos = __popcll(ms0) + __popcll(ms1 & ltmask);
            if (pos < KSEL) {
                selv[(size_t)t * KSEL + pos] = (f1 == 2) ? sv1 : (float)v1;
                seli[(size_t)t * KSEL + pos] = si1;
            }
        }
    }
}

// ---------------- Decode: 512 threads, j-range split + LDS combine ----------------
__global__ __launch_bounds__(512) void decode512(
    const float* __restrict__ selv, const int* __restrict__ seli,
    const unsigned short* __restrict__ Whf, const float* __restrict__ b2,
    float* __restrict__ out)
{
    const int t = blockIdx.x;
    const int tid = threadIdx.x;
    const int jh = tid >> 8;          // 0 or 1
    const int cpos = tid & 255;
    const int c = cpos * 4;
    __shared__ float sv[KSEL];
    __shared__ int si[KSEL];
    __shared__ float4 red[256];
    if (tid < KSEL) {
        sv[tid] = selv[(size_t)t * KSEL + tid];
        si[tid] = seli[(size_t)t * KSEL + tid];
    }
    __syncthreads();
    float4 acc = {0.f, 0.f, 0.f, 0.f};
    const int j0 = jh * 16;
#pragma unroll 8
    for (int j = j0; j < j0 + 16; ++j) {
        uint2 raw = *(const uint2*)&Whf[(size_t)si[j] * INPUT + c];
        const float s = sv[j];
        float2 f0 = __half22float2(*(__half2*)&raw.x);
        float2 f1 = __half22float2(*(__half2*)&raw.y);
        acc.x += s * f0.x; acc.y += s * f0.y; acc.z += s * f1.x; acc.w += s * f1.y;
    }
    if (jh == 1) red[cpos] = acc;
    __syncthreads();
    if (jh == 0) {
        float4 o = red[cpos];
        float4 bb = *(const float4*)&b2[c];
        o.x += acc.x + bb.x; o.y += acc.y + bb.y;
        o.z += acc.z + bb.z; o.w += acc.w + bb.w;
        *(float4*)&out[(size_t)t * INPUT + c] = o;
    }
}

extern "C" void kernel_launch(void* const* d_in, const int* in_sizes, int n_in,
                              void* d_out, int out_size, void* d_ws, size_t ws_size,
                              hipStream_t stream) {
    const float* x   = (const float*)d_in[0];
    const float* peb = (const float*)d_in[1];
    const float* W   = (const float*)d_in[2];
    const float* WT  = (const float*)d_in[3];
    const float* b1  = (const float*)d_in[4];
    const float* b2  = (const float*)d_in[5];
    float* out = (float*)d_out;

    char* p = (char*)d_ws;
    int*   candb = (int*)p;            p += (size_t)TOKENS * CANDCAP * 4;
    float* scrb  = (float*)p;          p += (size_t)TOKENS * CANDCAP * 4;
    int*   ncb   = (int*)p;            p += (size_t)TOKENS * 4;
    float* selvb = (float*)p;          p += (size_t)TOKENS * KSEL * 4;
    int*   selib = (int*)p;            p += (size_t)TOKENS * KSEL * 4;
    float* WTT   = (float*)p;          p += (size_t)HIDDEN * INPUT * 4;
    short* Abf   = (short*)p;          p += (size_t)TOKENS * INPUT * 2;
    short* Btb   = (short*)p;          p += (size_t)HIDDEN * INPUT * 2;
    unsigned short* Whf = (unsigned short*)p; p += (size_t)HIDDEN * INPUT * 2;
    unsigned short* pre16 = (unsigned short*)p;

    size_t used = (size_t)(p - (char*)d_ws);
    size_t avail = ws_size > used ? ws_size - used : 0;
    long cap = (long)(avail / ((size_t)HIDDEN * 2));
    cap = (cap / 256) * 256;
    if (cap > TOKENS) cap = TOKENS;   // single chunk if ws allows; auto-shrinks otherwise
    if (cap < 256) cap = 256;

    conv_x<<<dim3(TOKENS * INPUT / (256 * 8)), dim3(256), 0, stream>>>(x, peb, Abf);
    transp2<<<dim3(HIDDEN / 64, INPUT / 64), dim3(256), 0, stream>>>(WT, WTT, Btb);
    conv_whf<<<dim3((unsigned)((size_t)HIDDEN * INPUT / (256 * 8))), dim3(256), 0, stream>>>(W, Whf);

    for (int tok0 = 0; tok0 < TOKENS; tok0 += (int)cap) {
        int M = TOKENS - tok0;
        if (M > cap) M = (int)cap;
        gemm_bf16_256<<<dim3(HIDDEN / 256, M / 256), dim3(512), 0, stream>>>(
            Abf, Btb, b1, pre16, tok0);
        topcand3<<<dim3(M), dim3(256), 0, stream>>>(pre16, candb, scrb, ncb, tok0);
    }

    rescore_select_wave<<<dim3(TOKENS / 4), dim3(256), 0, stream>>>(
        x, peb, WTT, b1, candb, scrb, ncb, selvb, selib);
    decode512<<<dim3(TOKENS), dim3(512), 0, stream>>>(selvb, selib, Whf, b2, out);
}